// Round 3
// baseline (2896.560 us; speedup 1.0000x reference)
//
#include <hip/hip_runtime.h>
#include <hip/hip_bf16.h>

// TimeLSTM: B=2048, T=256, IN=65 (1 time-delta + 64 features), H=256, gates=1024.
//
// Round 3: W residency. 128 persistent blocks x 512 threads (8 waves, 2/SIMD).
// W (1024x320 bf16 = 640KB, pre-swizzled to MFMA B-frag order) is 3-tier:
//   kt 0..2  -> registers (24 frags/wave, 96 VGPR, loaded once before t-loop)
//   kt 3..4  -> LDS (16 frags/wave x 8 waves = 128KB, loaded once)
//   kt 5..9  -> streamed from L2 each step (320KB/CU/step), half-tile (4-frag)
//               pipeline with 2-deep lookahead so 4-8 loads stay in flight.
// __launch_bounds__(512,1): second arg acts as minBlocksPerCU on this toolchain
// (r2: (512,2) forced a 128-VGPR cap -> spills, WRITE_SIZE 21->87MB). (512,1)
// gives the 256-reg cap (8-wave block => 2 waves/SIMD).
// Barrier B moved BEFORE the MFMA phase (right after A-fragment LDS reads):
// MFMA+stream+epilogue+next-x-staging run barrier-free; wave skew absorbed.
//   step: stage x_t -> barrierA -> read a[10]+td from LDS -> barrierB ->
//         [prefetch x(t+1), MFMA kt0-9, epilogue, h->A]  (no barrier)
// Safety: all A/td reads complete before barrierB; h/x writes after barrierB
// touch regions only re-read after the NEXT barrierA.
// C/D layout (m89): col = lane&15, row = (lane>>4)*4 + reg.

typedef __bf16 v8bf __attribute__((ext_vector_type(8)));
typedef __bf16 v2bf __attribute__((ext_vector_type(2)));
typedef float f32x4 __attribute__((ext_vector_type(4)));

#define B_SZ 2048
#define T_SZ 256
#define IN_SZ 65
#define NKT 10          // 320 / 32 k-steps
#define MBLK 16
#define NBLOCKS (B_SZ / MBLK)   // 128
#define THREADS 512

#define LDSW_BYTES (8 * 16 * 1024)            // 128KB: 8 waves x 16 frags x 1KB
#define A_STRIDE 328                           // 320 + 8 bf16 pad
#define A_BYTES (16 * A_STRIDE * 2)            // 10496
#define SMEM_TOTAL (LDSW_BYTES + A_BYTES + 64 + 64)

__device__ __forceinline__ float fsig(float xv) {
    return __builtin_amdgcn_rcpf(1.f + __expf(-xv));
}
__device__ __forceinline__ float ftanh(float xv) {
    return fmaf(2.f, fsig(2.f * xv), -1.f);
}
// fragment id: wave (wq,wh) owns nt = g*4 + wh*2 + jt, i = g*2 + jt (g=0..3, jt=0..1)
__device__ __forceinline__ int fid(int kt, int wq, int wh, int i) {
    return (kt * 4 + wq) * 16 + (i >> 1) * 4 + wh * 2 + (i & 1);
}

// ---------------- prep: swizzle W into MFMA B-fragment order (bf16) ----------------
// 640 fragments (kt 0..9, wq 0..3, nt 0..15), 1KB each: total 640KB in d_ws.
// frag(kt,wq,nt): lane L holds W[n][k], n = (nt>>2)*256 + wq*64 + (nt&3)*16 + (L&15),
//                 k = kt*32 + (L>>4)*8 + j, j=0..7.
__global__ void prep_w(const float* __restrict__ W_ih, const float* __restrict__ W_hh,
                       __bf16* __restrict__ wsz) {
    int gtid = blockIdx.x * 256 + threadIdx.x;   // 0..40959
    int lane = gtid & 63;
    int frag = gtid >> 6;                        // 0..639
    int kt = frag >> 6;
    int wq = (frag >> 4) & 3;
    int nt = frag & 15;
    int g = nt >> 2, jt = nt & 3;
    int n  = g * 256 + wq * 64 + jt * 16 + (lane & 15);
    int k0 = kt * 32 + ((lane >> 4) << 3);
    v8bf v;
#pragma unroll
    for (int j = 0; j < 8; ++j) {
        int k = k0 + j;
        float f = (k < 64) ? W_ih[n * 64 + k] : W_hh[n * 256 + (k - 64)];
        v[j] = (__bf16)f;
    }
    *reinterpret_cast<v8bf*>(wsz + (size_t)frag * 512 + lane * 8) = v;
}

// ---------------- fused persistent scan ----------------
__global__ __launch_bounds__(THREADS, 1) void tlstm_scan(
    const float* __restrict__ x, const __bf16* __restrict__ wsz,
    const float* __restrict__ b_ih, const float* __restrict__ b_hh,
    const float* __restrict__ Wt, const float* __restrict__ bt,
    const float* __restrict__ Wf, const float* __restrict__ bfp,
    float* __restrict__ out) {
    extern __shared__ char smem[];
    __bf16* ldsW  = reinterpret_cast<__bf16*>(smem);                       // 128KB
    __bf16* A     = reinterpret_cast<__bf16*>(smem + LDSW_BYTES);          // 16 x 328 bf16
    float* td_lds = reinterpret_cast<float*>(smem + LDSW_BYTES + A_BYTES); // 16 f32
    float* out_acc = reinterpret_cast<float*>(smem + LDSW_BYTES + A_BYTES + 64);

    const int tid  = threadIdx.x;
    const int lane = tid & 63;
    const int w    = tid >> 6;     // 0..7
    const int wq   = w >> 1;       // 0..3  N-quadrant
    const int wh   = w & 1;        // 0..1  jt-pair within quadrant
    const int l15  = lane & 15;
    const int lhi  = lane >> 4;
    const int b0   = blockIdx.x * MBLK;

    const __bf16* wsz_l = wsz + (size_t)lane * 8;   // lane offset folded in

    // ---- one-time: register-resident W (kt 0..2): 24 frags, 96 VGPR
    v8bf wreg[24];
#pragma unroll
    for (int kt = 0; kt < 3; ++kt)
#pragma unroll
        for (int i = 0; i < 8; ++i)
            wreg[kt * 8 + i] = *reinterpret_cast<const v8bf*>(
                wsz_l + (size_t)fid(kt, wq, wh, i) * 512);

    // ---- one-time: LDS-resident W (kt 3..4): this wave's 16 frags -> its LDS slab
#pragma unroll
    for (int kt = 3; kt < 5; ++kt)
#pragma unroll
        for (int i = 0; i < 8; ++i)
            *reinterpret_cast<uint4*>(ldsW + ((size_t)(w * 16 + (kt - 3) * 8 + i) * 64 + lane) * 8) =
                *reinterpret_cast<const uint4*>(wsz_l + (size_t)fid(kt, wq, wh, i) * 512);

    // zero A (h region must start at 0)
    for (int i = tid; i < 16 * A_STRIDE; i += THREADS) A[i] = (__bf16)0.f;
    if (tid < 16) out_acc[tid] = 0.f;

    // per-lane constants: 2 column slots jt=0..1 at col = wq*64 + (wh*2+jt)*16 + l15
    float bias[4][2], wt_r[2], bt_r[2], wf_r[2];
#pragma unroll
    for (int jt = 0; jt < 2; ++jt) {
        int col = wq * 64 + (wh * 2 + jt) * 16 + l15;
#pragma unroll
        for (int g = 0; g < 4; ++g) bias[g][jt] = b_ih[g * 256 + col] + b_hh[g * 256 + col];
        wt_r[jt] = Wt[col];
        bt_r[jt] = bt[col];
        wf_r[jt] = Wf[col];
    }

    float cst[2][4];   // fp32 cell state: [jt][reg]
#pragma unroll
    for (int jt = 0; jt < 2; ++jt)
#pragma unroll
        for (int r = 0; r < 4; ++r) cst[jt][r] = 0.f;
    float outp[4] = {0.f, 0.f, 0.f, 0.f};

    // x staging: 512 threads cover 16 rows x 32 chunks of 2 features
    const int xr = tid >> 5;   // row 0..15
    const int xc = tid & 31;   // feature pair 0..31
    const float* xbase = x + (size_t)(b0 + xr) * T_SZ * IN_SZ;

    // prefetch x(t=0)
    float px0, px1, ptd = 0.f;
    {
        const float* p = xbase;
        px0 = p[1 + xc * 2];
        px1 = p[2 + xc * 2];
        if (xc == 0) ptd = p[0];
    }

    __syncthreads();           // ldsW + A zero visible

    for (int t = 0; t < T_SZ; ++t) {
        // ---- stage x_t (from prefetch regs) + td into LDS
        {
            v2bf vv;
            vv[0] = (__bf16)px0; vv[1] = (__bf16)px1;
            *reinterpret_cast<v2bf*>(A + xr * A_STRIDE + xc * 2) = vv;
            if (xc == 0) td_lds[xr] = ptd;
        }
        __syncthreads();   // barrier A: x_t + h(t-1) ready in LDS

        // ---- A fragments: lane holds A[m=l15][k = kt*32 + lhi*8 + 0..7]
        v8bf a[NKT];
#pragma unroll
        for (int kt = 0; kt < NKT; ++kt)
            a[kt] = *reinterpret_cast<const v8bf*>(A + l15 * A_STRIDE + kt * 32 + lhi * 8);
        f32x4 tdv = *reinterpret_cast<const f32x4*>(td_lds + lhi * 4);

        __syncthreads();   // barrier B: ALL LDS reads of this step done.
                           // Everything below is barrier-free until next barrier A.

        // ---- issue x(t+1) prefetch (overlaps GEMM)
        {
            int tn = (t + 1 < T_SZ) ? t + 1 : t;
            const float* p = xbase + (size_t)tn * IN_SZ;
            px0 = p[1 + xc * 2];
            px1 = p[2 + xc * 2];
            if (xc == 0) ptd = p[0];
        }

        f32x4 acc[8];
#pragma unroll
        for (int i = 0; i < 8; ++i) acc[i] = (f32x4){0.f, 0.f, 0.f, 0.f};

        // ---- stream prefetch: both halves of kt=5 (8 loads in flight)
        v8bf bs[2][4];
#pragma unroll
        for (int i = 0; i < 4; ++i)
            bs[0][i] = *reinterpret_cast<const v8bf*>(wsz_l + (size_t)fid(5, wq, wh, i) * 512);
#pragma unroll
        for (int i = 0; i < 4; ++i)
            bs[1][i] = *reinterpret_cast<const v8bf*>(wsz_l + (size_t)fid(5, wq, wh, 4 + i) * 512);

        // ---- kt 0..2 from registers (hides first stream latency)
#pragma unroll
        for (int kt = 0; kt < 3; ++kt)
#pragma unroll
            for (int i = 0; i < 8; ++i)
                acc[i] = __builtin_amdgcn_mfma_f32_16x16x32_bf16(a[kt], wreg[kt * 8 + i], acc[i], 0, 0, 0);

        // ---- kt 3..4 from LDS
#pragma unroll
        for (int kt = 3; kt < 5; ++kt)
#pragma unroll
            for (int i = 0; i < 8; ++i) {
                v8bf b = *reinterpret_cast<const v8bf*>(
                    ldsW + ((size_t)(w * 16 + (kt - 3) * 8 + i) * 64 + lane) * 8);
                acc[i] = __builtin_amdgcn_mfma_f32_16x16x32_bf16(a[kt], b, acc[i], 0, 0, 0);
            }

        // ---- kt 5..9 streamed: half-tile (4-frag) pipeline, prefetch 2 ahead
#pragma unroll
        for (int s = 0; s < 10; ++s) {
            int kt = 5 + (s >> 1);
            int ib = (s & 1) * 4;
#pragma unroll
            for (int i = 0; i < 4; ++i)
                acc[ib + i] = __builtin_amdgcn_mfma_f32_16x16x32_bf16(a[kt], bs[s & 1][i], acc[ib + i], 0, 0, 0);
            if (s < 8) {   // prefetch half-tile s+2 into the buffer just consumed
                int kn = 5 + ((s + 2) >> 1);
#pragma unroll
                for (int i = 0; i < 4; ++i)
                    bs[s & 1][i] = *reinterpret_cast<const v8bf*>(
                        wsz_l + (size_t)fid(kn, wq, wh, ib + i) * 512);
            }
        }

        // ---- lane-local LSTM epilogue (all 4 gates for this lane's 2 columns)
        const bool last = (t == T_SZ - 1);
#pragma unroll
        for (int jt = 0; jt < 2; ++jt) {
#pragma unroll
            for (int r = 0; r < 4; ++r) {
                float pi = acc[0 * 2 + jt][r] + bias[0][jt];
                float pf = acc[1 * 2 + jt][r] + bias[1][jt];
                float pg = acc[2 * 2 + jt][r] + bias[2][jt];
                float po = acc[3 * 2 + jt][r] + bias[3][jt];
                float d  = fsig(fmaf(tdv[r], wt_r[jt], bt_r[jt]));
                float c  = cst[jt][r] * d;                    // c *= decay
                c = fsig(pf) * c + fsig(pi) * ftanh(pg);      // c = f*c + i*g
                cst[jt][r] = c;
                float h = fsig(po) * ftanh(c);                // h = o*tanh(c)
                int row = lhi * 4 + r;
                int col = wq * 64 + (wh * 2 + jt) * 16 + l15;
                A[row * A_STRIDE + 64 + col] = (__bf16)h;     // h -> A layout for next step
                if (last) outp[r] = fmaf(h, wf_r[jt], outp[r]);
            }
        }
    }

    // ---- output: out[b] = h_T . Wf + bf
#pragma unroll
    for (int r = 0; r < 4; ++r) atomicAdd(&out_acc[lhi * 4 + r], outp[r]);
    __syncthreads();
    if (tid < 16) out[b0 + tid] = out_acc[tid] + bfp[0];
}

extern "C" void kernel_launch(void* const* d_in, const int* in_sizes, int n_in,
                              void* d_out, int out_size, void* d_ws, size_t ws_size,
                              hipStream_t stream) {
    const float* x    = (const float*)d_in[0];
    const float* W_ih = (const float*)d_in[1];
    const float* W_hh = (const float*)d_in[2];
    const float* b_ih = (const float*)d_in[3];
    const float* b_hh = (const float*)d_in[4];
    const float* Wt   = (const float*)d_in[5];
    const float* bt   = (const float*)d_in[6];
    const float* Wf   = (const float*)d_in[7];
    const float* bfp  = (const float*)d_in[8];
    float* out  = (float*)d_out;
    __bf16* wsz = (__bf16*)d_ws;   // 640KB of swizzled bf16 W

    (void)in_sizes; (void)n_in; (void)out_size; (void)ws_size;

    hipFuncSetAttribute(reinterpret_cast<const void*>(tlstm_scan),
                        hipFuncAttributeMaxDynamicSharedMemorySize, SMEM_TOTAL);

    prep_w<<<dim3(160), dim3(256), 0, stream>>>(W_ih, W_hh, wsz);
    tlstm_scan<<<dim3(NBLOCKS), dim3(THREADS), SMEM_TOTAL, stream>>>(
        x, wsz, b_ih, b_hh, Wt, bt, Wf, bfp, out);
}